// Round 4
// baseline (1459.476 us; speedup 1.0000x reference)
//
#include <hip/hip_runtime.h>
#include <hip/hip_bf16.h>
#include <cstdint>

#define BN_EPS 1e-5f

typedef __attribute__((ext_vector_type(8))) short bf16x8;
typedef __attribute__((ext_vector_type(4))) float f32x4;

__device__ inline void fatomadd(float* p, float v) { unsafeAtomicAdd(p, v); }

__device__ inline unsigned short f2bf(float f) {
  unsigned int b = __float_as_uint(f);
  b += 0x7FFFu + ((b >> 16) & 1u);  // RNE
  return (unsigned short)(b >> 16);
}
__device__ inline float bf2f(unsigned short u) { return __uint_as_float((unsigned int)u << 16); }

// ---------------- pack weights: bf16, transposed [Ncols][K] ----------------
__global__ void pack_b1t(const float* __restrict__ W1, const float* __restrict__ root1,
                         const float* __restrict__ Wskip, __hip_bfloat16* __restrict__ B1t) {
  int idx = blockIdx.x * blockDim.x + threadIdx.x;
  if (idx >= 640 * 32) return;
  int n = idx >> 5, k = idx & 31;
  float v;
  if (n < 512) v = W1[(n & 7) * (32 * 64) + k * 64 + (n >> 3)];
  else if (n < 576) v = root1[k * 64 + (n - 512)];
  else v = Wskip[k * 64 + (n - 576)];
  ((unsigned short*)B1t)[idx] = f2bf(v);
}

__global__ void pack_b2t(const float* __restrict__ W2, const float* __restrict__ root2,
                         __hip_bfloat16* __restrict__ B2t) {
  int idx = blockIdx.x * blockDim.x + threadIdx.x;
  if (idx >= 576 * 64) return;
  int n = idx >> 6, k = idx & 63;
  float v;
  if (n < 512) v = W2[(n & 7) * (64 * 64) + k * 64 + (n >> 3)];
  else v = root2[k * 64 + (n - 512)];
  ((unsigned short*)B2t)[idx] = f2bf(v);
}

// ---------------- edge preprocessing: src-grouped permutation ----------------
__global__ void edge_hist(const int* __restrict__ ei, int E, int* __restrict__ odeg,
                          float* __restrict__ cnt) {
  int e = blockIdx.x * 256 + threadIdx.x;
  if (e >= E) return;
  atomicAdd(&odeg[ei[e]], 1);
  fatomadd(&cnt[ei[E + e]], 1.f);
}

__global__ __launch_bounds__(1024) void scan_exclusive(const int* __restrict__ odeg,
                                                       int* __restrict__ cursor, int N) {
  __shared__ int tmp[1024];
  __shared__ int carry_s;
  if (threadIdx.x == 0) carry_s = 0;
  __syncthreads();
  for (int base = 0; base < N; base += 1024) {
    int i = base + threadIdx.x;
    int v = (i < N) ? odeg[i] : 0;
    tmp[threadIdx.x] = v;
    __syncthreads();
    for (int ofs = 1; ofs < 1024; ofs <<= 1) {
      int t = (threadIdx.x >= (unsigned)ofs) ? tmp[threadIdx.x - ofs] : 0;
      __syncthreads();
      tmp[threadIdx.x] += t;
      __syncthreads();
    }
    if (i < N) cursor[i] = carry_s + tmp[threadIdx.x] - v;
    __syncthreads();
    if (threadIdx.x == 1023) carry_s += tmp[1023];
    __syncthreads();
  }
}

__global__ void edge_scatter(const int* __restrict__ ei, const float* __restrict__ attr, int E,
                             int* __restrict__ cursor, int* __restrict__ ssrc,
                             int* __restrict__ sdst, float* __restrict__ sattr) {
  int e = blockIdx.x * 256 + threadIdx.x;
  if (e >= E) return;
  int src = ei[e], dst = ei[E + e];
  int pos = atomicAdd(&cursor[src], 1);
  ssrc[pos] = src;
  sdst[pos] = dst;
  sattr[3 * pos + 0] = attr[3 * e + 0];
  sattr[3 * pos + 1] = attr[3 * e + 1];
  sattr[3 * pos + 2] = attr[3 * e + 2];
}

// ---------------- MFMA GEMM: C(M x Ncols bf16) = A(M x K fp32) @ Bt(Ncols x K bf16)^T ----------
template <int K, bool BN>
__global__ __launch_bounds__(256) void gemm_mfma(const float* __restrict__ A,
                                                 const __hip_bfloat16* __restrict__ Bt,
                                                 __hip_bfloat16* __restrict__ C, int M, int Ncols,
                                                 const float* __restrict__ scale,
                                                 const float* __restrict__ shift) {
  const int tid = threadIdx.x;
  const int lane = tid & 63;
  const int wv = tid >> 6;
  const int rowbase = blockIdx.x * 64 + wv * 16;
  const int m = lane & 15;
  const int quad = lane >> 4;
  const int k0 = quad * 8;

  int ar = rowbase + m;
  if (ar > M - 1) ar = M - 1;
  const float* arow = A + (size_t)ar * K;

  bf16x8 afrag[K / 32];
#pragma unroll
  for (int f = 0; f < K / 32; f++) {
    float v[8];
#pragma unroll
    for (int j = 0; j < 8; j++) v[j] = arow[f * 32 + k0 + j];
    if (BN) {
#pragma unroll
      for (int j = 0; j < 8; j++) {
        float t = v[j] * scale[f * 32 + k0 + j] + shift[f * 32 + k0 + j];
        v[j] = t > 0.f ? t : expm1f(t);
      }
    }
    bf16x8 af;
#pragma unroll
    for (int j = 0; j < 8; j++) af[j] = (short)f2bf(v[j]);
    afrag[f] = af;
  }

  for (int col0 = 0; col0 < Ncols; col0 += 16) {
    f32x4 acc = {0.f, 0.f, 0.f, 0.f};
#pragma unroll
    for (int f = 0; f < K / 32; f++) {
      const __hip_bfloat16* bp = Bt + (size_t)(col0 + m) * K + f * 32 + k0;
      bf16x8 bfrag = *(const bf16x8*)bp;
      acc = __builtin_amdgcn_mfma_f32_16x16x32_bf16(afrag[f], bfrag, acc, 0, 0, 0);
    }
#pragma unroll
    for (int r = 0; r < 4; r++) {
      int gr = rowbase + quad * 4 + r;
      if (gr < M) ((unsigned short*)C)[(size_t)gr * Ncols + col0 + m] = f2bf(acc[r]);
    }
  }
}

// ---------------- per-edge message over src-grouped edges ----------------
__global__ __launch_bounds__(256) void msg_kernel2(const __hip_bfloat16* __restrict__ Y, int ystride,
                                                   const int* __restrict__ ssrc,
                                                   const int* __restrict__ sdst,
                                                   const float* __restrict__ sattr, int E,
                                                   float* __restrict__ agg) {
  long long gid = (long long)blockIdx.x * blockDim.x + threadIdx.x;
  int e = (int)(gid >> 6);
  if (e >= E) return;
  int lane = (int)(gid & 63);
  int src = ssrc[e];
  int dst = sdst[e];
  float u0 = sattr[3 * e + 0], u1 = sattr[3 * e + 1], u2 = sattr[3 * e + 2];
  float p0 = 1.f - u0, p1 = 1.f - u1, p2 = 1.f - u2;
  float w[8];
  w[0] = p0 * p1 * p2; w[1] = u0 * p1 * p2;
  w[2] = p0 * u1 * p2; w[3] = u0 * u1 * p2;
  w[4] = p0 * p1 * u2; w[5] = u0 * p1 * u2;
  w[6] = p0 * u1 * u2; w[7] = u0 * u1 * u2;
  const __hip_bfloat16* yr = Y + (size_t)src * ystride + lane * 8;
  union { float4 f4; unsigned short us[8]; } u;
  u.f4 = *(const float4*)yr;
  float m = 0.f;
#pragma unroll
  for (int k = 0; k < 8; k++) m += w[k] * bf2f(u.us[k]);
  fatomadd(&agg[(size_t)dst * 64 + lane], m);
}

// ---------------- finish layer1 (in-place) ----------------
__global__ __launch_bounds__(256) void finish1(float* __restrict__ agg,
                                               const float* __restrict__ cnt,
                                               const __hip_bfloat16* __restrict__ ybuf, int N,
                                               float* __restrict__ spre,
                                               double* __restrict__ sums /* 4x64 */) {
  int tid = threadIdx.x;
  int ch = tid & 63, slot = tid >> 6;
  float sh = 0.f, sh2 = 0.f, ss = 0.f, ss2 = 0.f;
  for (int n = blockIdx.x * 4 + slot; n < N; n += gridDim.x * 4) {
    float inv = 1.f / fmaxf(cnt[n], 1.f);
    float h = agg[(size_t)n * 64 + ch] * inv + bf2f(((const unsigned short*)ybuf)[(size_t)n * 640 + 512 + ch]);
    float s = bf2f(((const unsigned short*)ybuf)[(size_t)n * 640 + 576 + ch]);
    agg[(size_t)n * 64 + ch] = h;
    spre[(size_t)n * 64 + ch] = s;
    sh += h; sh2 += h * h; ss += s; ss2 += s * s;
  }
  __shared__ float red[256];
  float vals[4] = {sh, sh2, ss, ss2};
  for (int v = 0; v < 4; v++) {
    __syncthreads();
    red[tid] = vals[v];
    __syncthreads();
    if (tid < 64) {
      float tot = red[tid] + red[tid + 64] + red[tid + 128] + red[tid + 192];
      atomicAdd(&sums[v * 64 + tid], (double)tot);
    }
  }
}

// ---------------- finish layer2 (in-place) ----------------
__global__ __launch_bounds__(256) void finish2(float* __restrict__ agg,
                                               const float* __restrict__ cnt,
                                               const __hip_bfloat16* __restrict__ ybuf, int N,
                                               double* __restrict__ sums /* 2x64 */) {
  int tid = threadIdx.x;
  int ch = tid & 63, slot = tid >> 6;
  float sh = 0.f, sh2 = 0.f;
  for (int n = blockIdx.x * 4 + slot; n < N; n += gridDim.x * 4) {
    float inv = 1.f / fmaxf(cnt[n], 1.f);
    float h = agg[(size_t)n * 64 + ch] * inv + bf2f(((const unsigned short*)ybuf)[(size_t)n * 576 + 512 + ch]);
    agg[(size_t)n * 64 + ch] = h;
    sh += h; sh2 += h * h;
  }
  __shared__ float red[256];
  float vals[2] = {sh, sh2};
  for (int v = 0; v < 2; v++) {
    __syncthreads();
    red[tid] = vals[v];
    __syncthreads();
    if (tid < 64) {
      float tot = red[tid] + red[tid + 64] + red[tid + 128] + red[tid + 192];
      atomicAdd(&sums[v * 64 + tid], (double)tot);
    }
  }
}

// ---------------- bn finalize ----------------
__global__ void bn_finalize(const double* __restrict__ sums /*2x64*/, const float* __restrict__ g,
                            const float* __restrict__ b, float* __restrict__ scale,
                            float* __restrict__ shift, int N) {
  int t = threadIdx.x;
  if (t >= 64) return;
  double mean = sums[t] / (double)N;
  double var = sums[64 + t] / (double)N - mean * mean;
  double inv = 1.0 / sqrt(var + (double)BN_EPS);
  float sc = (float)((double)g[t] * inv);
  scale[t] = sc;
  shift[t] = b[t] - (float)mean * sc;
}

// ---------------- epilogue ----------------
__global__ __launch_bounds__(256) void final_k(const float* __restrict__ h2pre,
                                               const float* __restrict__ scale2,
                                               const float* __restrict__ shift2,
                                               const float* __restrict__ scaleS,
                                               const float* __restrict__ shiftS,
                                               float* __restrict__ out, int total) {
  int idx = blockIdx.x * 256 + threadIdx.x;
  if (idx >= total) return;
  int ch = idx & 63;
  float h2 = h2pre[idx] * scale2[ch] + shift2[ch];
  float s = out[idx] * scaleS[ch] + shiftS[ch];
  float v = h2 + s;
  out[idx] = v > 0.f ? v : expm1f(v);
}

extern "C" void kernel_launch(void* const* d_in, const int* in_sizes, int n_in,
                              void* d_out, int out_size, void* d_ws, size_t ws_size,
                              hipStream_t stream) {
  const float* x     = (const float*)d_in[0];
  const int*   ei    = (const int*)d_in[1];
  const float* attr  = (const float*)d_in[2];
  const float* W1    = (const float*)d_in[3];
  const float* root1 = (const float*)d_in[4];
  const float* g1    = (const float*)d_in[5];
  const float* b1    = (const float*)d_in[6];
  const float* W2    = (const float*)d_in[7];
  const float* root2 = (const float*)d_in[8];
  const float* g2    = (const float*)d_in[9];
  const float* b2    = (const float*)d_in[10];
  const float* Wskip = (const float*)d_in[11];
  const float* gS    = (const float*)d_in[12];
  const float* bS    = (const float*)d_in[13];
  const int N = in_sizes[0] / 32;
  const int E = in_sizes[1] / 2;
  float* out = (float*)d_out;

  char* ws = (char*)d_ws;
  size_t off = 0;
  auto alloc = [&](size_t bytes) {
    void* p = ws + off;
    off = (off + bytes + 255) & ~(size_t)255;
    return p;
  };
  __hip_bfloat16* B1t = (__hip_bfloat16*)alloc(640 * 32 * 2);
  __hip_bfloat16* B2t = (__hip_bfloat16*)alloc(576 * 64 * 2);
  double* sums   = (double*)alloc(6 * 64 * 8);
  float*  scales = (float*)alloc(6 * 64 * 4);
  float*  cnt    = (float*)alloc((size_t)N * 4);
  int*    odeg   = (int*)alloc((size_t)N * 4);
  int*    cursor = (int*)alloc((size_t)N * 4);
  int*    ssrc   = (int*)alloc((size_t)E * 4);
  int*    sdst   = (int*)alloc((size_t)E * 4);
  float*  sattr  = (float*)alloc((size_t)E * 12);
  float*  agg    = (float*)alloc((size_t)N * 64 * 4);                 // hpre1 then h2pre in place
  __hip_bfloat16* ybuf = (__hip_bfloat16*)alloc((size_t)N * 640 * 2); // Y1ext(640) / Y2ext(576)
  if (off > ws_size) return;  // workspace too small: fail gracefully

  hipMemsetAsync(cnt, 0, (size_t)N * 4, stream);
  hipMemsetAsync(odeg, 0, (size_t)N * 4, stream);
  hipMemsetAsync(agg, 0, (size_t)N * 64 * 4, stream);
  hipMemsetAsync(sums, 0, 6 * 64 * 8, stream);

  pack_b1t<<<(640 * 32 + 255) / 256, 256, 0, stream>>>(W1, root1, Wskip, B1t);
  pack_b2t<<<(576 * 64 + 255) / 256, 256, 0, stream>>>(W2, root2, B2t);

  const int eblocks = (E + 255) / 256;
  edge_hist<<<eblocks, 256, 0, stream>>>(ei, E, odeg, cnt);
  scan_exclusive<<<1, 1024, 0, stream>>>(odeg, cursor, N);
  edge_scatter<<<eblocks, 256, 0, stream>>>(ei, attr, E, cursor, ssrc, sdst, sattr);

  const int gblocks = (N + 63) / 64;

  // layer 1: Y1ext = x @ [W1(o-major)|root1|Wskip]   (N x 640, bf16)
  gemm_mfma<32, false><<<gblocks, 256, 0, stream>>>(x, B1t, ybuf, N, 640, nullptr, nullptr);

  long long mthreads = (long long)E * 64;
  int mblocks = (int)((mthreads + 255) / 256);
  msg_kernel2<<<mblocks, 256, 0, stream>>>(ybuf, 640, ssrc, sdst, sattr, E, agg);

  finish1<<<1024, 256, 0, stream>>>(agg, cnt, ybuf, N, out, sums);
  bn_finalize<<<1, 64, 0, stream>>>(sums + 0 * 64, g1, b1, scales + 0 * 64, scales + 1 * 64, N);
  bn_finalize<<<1, 64, 0, stream>>>(sums + 2 * 64, gS, bS, scales + 2 * 64, scales + 3 * 64, N);

  // layer 2: Y2ext = elu(bn1(hpre)) @ [W2(o-major)|root2]   (N x 576, bf16)
  gemm_mfma<64, true><<<gblocks, 256, 0, stream>>>(agg, B2t, ybuf, N, 576, scales + 0 * 64,
                                                   scales + 1 * 64);

  hipMemsetAsync(agg, 0, (size_t)N * 64 * 4, stream);
  msg_kernel2<<<mblocks, 256, 0, stream>>>(ybuf, 576, ssrc, sdst, sattr, E, agg);

  finish2<<<1024, 256, 0, stream>>>(agg, cnt, ybuf, N, sums + 4 * 64);
  bn_finalize<<<1, 64, 0, stream>>>(sums + 4 * 64, g2, b2, scales + 4 * 64, scales + 5 * 64, N);

  final_k<<<((N * 64) + 255) / 256, 256, 0, stream>>>(agg, scales + 4 * 64, scales + 5 * 64,
                                                      scales + 2 * 64, scales + 3 * 64, out,
                                                      N * 64);
}

// Round 5
// 925.101 us; speedup vs baseline: 1.5776x; 1.5776x over previous
//
#include <hip/hip_runtime.h>
#include <hip/hip_bf16.h>
#include <cstdint>

#define BN_EPS 1e-5f

typedef __attribute__((ext_vector_type(8))) short bf16x8;
typedef __attribute__((ext_vector_type(4))) float f32x4;

__device__ inline void fatomadd(float* p, float v) { unsafeAtomicAdd(p, v); }

__device__ inline unsigned short f2bf(float f) {
  unsigned int b = __float_as_uint(f);
  b += 0x7FFFu + ((b >> 16) & 1u);  // RNE
  return (unsigned short)(b >> 16);
}
__device__ inline float bf2f(unsigned short u) { return __uint_as_float((unsigned int)u << 16); }

// ---------------- pack weights: bf16, transposed [Ncols][K] ----------------
__global__ void pack_b1t(const float* __restrict__ W1, const float* __restrict__ root1,
                         const float* __restrict__ Wskip, __hip_bfloat16* __restrict__ B1t) {
  int idx = blockIdx.x * blockDim.x + threadIdx.x;
  if (idx >= 640 * 32) return;
  int n = idx >> 5, k = idx & 31;
  float v;
  if (n < 512) v = W1[(n & 7) * (32 * 64) + k * 64 + (n >> 3)];
  else if (n < 576) v = root1[k * 64 + (n - 512)];
  else v = Wskip[k * 64 + (n - 576)];
  ((unsigned short*)B1t)[idx] = f2bf(v);
}

__global__ void pack_b2t(const float* __restrict__ W2, const float* __restrict__ root2,
                         __hip_bfloat16* __restrict__ B2t) {
  int idx = blockIdx.x * blockDim.x + threadIdx.x;
  if (idx >= 576 * 64) return;
  int n = idx >> 6, k = idx & 63;
  float v;
  if (n < 512) v = W2[(n & 7) * (64 * 64) + k * 64 + (n >> 3)];
  else v = root2[k * 64 + (n - 512)];
  ((unsigned short*)B2t)[idx] = f2bf(v);
}

// ---------------- dst-CSR build ----------------
__global__ void hist_dst(const int* __restrict__ ei, int E, int* __restrict__ indeg) {
  int e = blockIdx.x * 256 + threadIdx.x;
  if (e >= E) return;
  atomicAdd(&indeg[ei[E + e]], 1);
}

__global__ __launch_bounds__(1024) void scan_block(const int* __restrict__ in,
                                                   int* __restrict__ part,
                                                   int* __restrict__ bsum, int N) {
  __shared__ int tmp[1024];
  int i = blockIdx.x * 1024 + threadIdx.x;
  int v = (i < N) ? in[i] : 0;
  tmp[threadIdx.x] = v;
  __syncthreads();
  for (int ofs = 1; ofs < 1024; ofs <<= 1) {
    int t = (threadIdx.x >= (unsigned)ofs) ? tmp[threadIdx.x - ofs] : 0;
    __syncthreads();
    tmp[threadIdx.x] += t;
    __syncthreads();
  }
  if (i < N) part[i] = tmp[threadIdx.x] - v;  // exclusive within block
  if (threadIdx.x == 1023) bsum[blockIdx.x] = tmp[1023];
}

__global__ __launch_bounds__(1024) void scan_top(int* __restrict__ bsum, int nb) {
  __shared__ int tmp[1024];
  int v = (threadIdx.x < (unsigned)nb) ? bsum[threadIdx.x] : 0;
  tmp[threadIdx.x] = v;
  __syncthreads();
  for (int ofs = 1; ofs < 1024; ofs <<= 1) {
    int t = (threadIdx.x >= (unsigned)ofs) ? tmp[threadIdx.x - ofs] : 0;
    __syncthreads();
    tmp[threadIdx.x] += t;
    __syncthreads();
  }
  if (threadIdx.x < (unsigned)nb) bsum[threadIdx.x] = tmp[threadIdx.x] - v;  // exclusive
}

__global__ void scan_add(const int* __restrict__ part, const int* __restrict__ bsum,
                         int* __restrict__ rowptr, int* __restrict__ cursor, int N, int E) {
  int i = blockIdx.x * 256 + threadIdx.x;
  if (i < N) {
    int r = part[i] + bsum[i >> 10];
    rowptr[i] = r;
    cursor[i] = r;
  }
  if (i == 0) rowptr[N] = E;
}

// emeta[pos] = {u0, u1, u2, bits(src)} grouped by dst
__global__ void edge_scatter(const int* __restrict__ ei, const float* __restrict__ attr, int E,
                             int* __restrict__ cursor, float4* __restrict__ emeta) {
  int e = blockIdx.x * 256 + threadIdx.x;
  if (e >= E) return;
  int src = ei[e], dst = ei[E + e];
  int pos = atomicAdd(&cursor[dst], 1);
  emeta[pos] = make_float4(attr[3 * e + 0], attr[3 * e + 1], attr[3 * e + 2],
                           __int_as_float(src));
}

// ---------------- MFMA GEMM: C(M x Ncols bf16) = A(M x K fp32) @ Bt(Ncols x K bf16)^T ----------
template <int K, bool BN>
__global__ __launch_bounds__(256) void gemm_mfma(const float* __restrict__ A,
                                                 const __hip_bfloat16* __restrict__ Bt,
                                                 __hip_bfloat16* __restrict__ C, int M, int Ncols,
                                                 const float* __restrict__ scale,
                                                 const float* __restrict__ shift) {
  const int tid = threadIdx.x;
  const int lane = tid & 63;
  const int wv = tid >> 6;
  const int rowbase = blockIdx.x * 64 + wv * 16;
  const int m = lane & 15;
  const int quad = lane >> 4;
  const int k0 = quad * 8;

  int ar = rowbase + m;
  if (ar > M - 1) ar = M - 1;
  const float* arow = A + (size_t)ar * K;

  bf16x8 afrag[K / 32];
#pragma unroll
  for (int f = 0; f < K / 32; f++) {
    float v[8];
#pragma unroll
    for (int j = 0; j < 8; j++) v[j] = arow[f * 32 + k0 + j];
    if (BN) {
#pragma unroll
      for (int j = 0; j < 8; j++) {
        float t = v[j] * scale[f * 32 + k0 + j] + shift[f * 32 + k0 + j];
        v[j] = t > 0.f ? t : expm1f(t);
      }
    }
    bf16x8 af;
#pragma unroll
    for (int j = 0; j < 8; j++) af[j] = (short)f2bf(v[j]);
    afrag[f] = af;
  }

  for (int col0 = 0; col0 < Ncols; col0 += 16) {
    f32x4 acc = {0.f, 0.f, 0.f, 0.f};
#pragma unroll
    for (int f = 0; f < K / 32; f++) {
      const __hip_bfloat16* bp = Bt + (size_t)(col0 + m) * K + f * 32 + k0;
      bf16x8 bfrag = *(const bf16x8*)bp;
      acc = __builtin_amdgcn_mfma_f32_16x16x32_bf16(afrag[f], bfrag, acc, 0, 0, 0);
    }
#pragma unroll
    for (int r = 0; r < 4; r++) {
      int gr = rowbase + quad * 4 + r;
      if (gr < M) ((unsigned short*)C)[(size_t)gr * Ncols + col0 + m] = f2bf(acc[r]);
    }
  }
}

// ---------------- dst-grouped message + finish (fused): one wave per dst node ----------------
// Lane = output channel. Accumulates in registers (no atomics), then
// h = acc/deg + root-term, optional s = skip-term, plus per-channel BN partial sums.
template <int YSTRIDE, bool L1>
__global__ __launch_bounds__(256) void msg_dst(const __hip_bfloat16* __restrict__ Y,
                                               const int* __restrict__ rowptr,
                                               const float4* __restrict__ emeta, int N,
                                               float* __restrict__ hout,
                                               float* __restrict__ sout,
                                               double* __restrict__ sums) {
  const int tid = threadIdx.x;
  const int lane = tid & 63;
  const int wv = tid >> 6;
  const int nwaves = gridDim.x * 4;
  float sh = 0.f, sh2 = 0.f, ss = 0.f, ss2 = 0.f;

  for (int n = blockIdx.x * 4 + wv; n < N; n += nwaves) {
    const int e0 = rowptr[n], e1 = rowptr[n + 1];
    float acc = 0.f;
    for (int e = e0; e < e1; e++) {
      float4 md = emeta[e];
      int src = __float_as_int(md.w);
      float u0 = md.x, u1 = md.y, u2 = md.z;
      float p0 = 1.f - u0, p1 = 1.f - u1, p2 = 1.f - u2;
      float w00 = p1 * p2, w10 = u1 * p2, w01 = p1 * u2, w11 = u1 * u2;
      const unsigned short* yr = (const unsigned short*)Y + (size_t)src * YSTRIDE + lane * 8;
      union { bf16x8 v8; unsigned short us[8]; } u;
      u.v8 = *(const bf16x8*)yr;
      float m = (p0 * w00) * bf2f(u.us[0]) + (u0 * w00) * bf2f(u.us[1]) +
                (p0 * w10) * bf2f(u.us[2]) + (u0 * w10) * bf2f(u.us[3]) +
                (p0 * w01) * bf2f(u.us[4]) + (u0 * w01) * bf2f(u.us[5]) +
                (p0 * w11) * bf2f(u.us[6]) + (u0 * w11) * bf2f(u.us[7]);
      acc += m;
    }
    float inv = 1.f / fmaxf((float)(e1 - e0), 1.f);
    float h = acc * inv +
              bf2f(((const unsigned short*)Y)[(size_t)n * YSTRIDE + 512 + lane]);
    hout[(size_t)n * 64 + lane] = h;
    sh += h; sh2 += h * h;
    if (L1) {
      float s = bf2f(((const unsigned short*)Y)[(size_t)n * YSTRIDE + 576 + lane]);
      sout[(size_t)n * 64 + lane] = s;
      ss += s; ss2 += s * s;
    }
  }

  // block-level reduction of per-channel stats, then one double-atomic per channel/stat
  __shared__ float red[256];
  const int nst = L1 ? 4 : 2;
  float vals[4] = {sh, sh2, ss, ss2};
  for (int v = 0; v < nst; v++) {
    __syncthreads();
    red[tid] = vals[v];
    __syncthreads();
    if (tid < 64) {
      float tot = red[tid] + red[tid + 64] + red[tid + 128] + red[tid + 192];
      atomicAdd(&sums[v * 64 + tid], (double)tot);
    }
  }
}

// ---------------- bn finalize ----------------
__global__ void bn_finalize(const double* __restrict__ sums /*2x64*/, const float* __restrict__ g,
                            const float* __restrict__ b, float* __restrict__ scale,
                            float* __restrict__ shift, int N) {
  int t = threadIdx.x;
  if (t >= 64) return;
  double mean = sums[t] / (double)N;
  double var = sums[64 + t] / (double)N - mean * mean;
  double inv = 1.0 / sqrt(var + (double)BN_EPS);
  float sc = (float)((double)g[t] * inv);
  scale[t] = sc;
  shift[t] = b[t] - (float)mean * sc;
}

// ---------------- epilogue: out = elu(bn2(h2pre) + bnS(spre)); spre lives in d_out ----------------
__global__ __launch_bounds__(256) void final_k(const float* __restrict__ h2pre,
                                               const float* __restrict__ scale2,
                                               const float* __restrict__ shift2,
                                               const float* __restrict__ scaleS,
                                               const float* __restrict__ shiftS,
                                               float* __restrict__ out, int total) {
  int idx = blockIdx.x * 256 + threadIdx.x;
  if (idx >= total) return;
  int ch = idx & 63;
  float h2 = h2pre[idx] * scale2[ch] + shift2[ch];
  float s = out[idx] * scaleS[ch] + shiftS[ch];
  float v = h2 + s;
  out[idx] = v > 0.f ? v : expm1f(v);
}

extern "C" void kernel_launch(void* const* d_in, const int* in_sizes, int n_in,
                              void* d_out, int out_size, void* d_ws, size_t ws_size,
                              hipStream_t stream) {
  const float* x     = (const float*)d_in[0];
  const int*   ei    = (const int*)d_in[1];
  const float* attr  = (const float*)d_in[2];
  const float* W1    = (const float*)d_in[3];
  const float* root1 = (const float*)d_in[4];
  const float* g1    = (const float*)d_in[5];
  const float* b1    = (const float*)d_in[6];
  const float* W2    = (const float*)d_in[7];
  const float* root2 = (const float*)d_in[8];
  const float* g2    = (const float*)d_in[9];
  const float* b2    = (const float*)d_in[10];
  const float* Wskip = (const float*)d_in[11];
  const float* gS    = (const float*)d_in[12];
  const float* bS    = (const float*)d_in[13];
  const int N = in_sizes[0] / 32;
  const int E = in_sizes[1] / 2;
  float* out = (float*)d_out;

  char* ws = (char*)d_ws;
  size_t off = 0;
  auto alloc = [&](size_t bytes) {
    void* p = ws + off;
    off = (off + bytes + 255) & ~(size_t)255;
    return p;
  };
  __hip_bfloat16* B1t = (__hip_bfloat16*)alloc(640 * 32 * 2);
  __hip_bfloat16* B2t = (__hip_bfloat16*)alloc(576 * 64 * 2);
  double* sums   = (double*)alloc(6 * 64 * 8);
  float*  scales = (float*)alloc(6 * 64 * 4);
  int*    indeg  = (int*)alloc((size_t)N * 4);
  int*    rowptr = (int*)alloc(((size_t)N + 1) * 4);
  int*    cursor = (int*)alloc((size_t)N * 4);
  int*    bsum   = (int*)alloc(1024 * 4);
  float4* emeta  = (float4*)alloc((size_t)E * 16);
  float*  agg    = (float*)alloc((size_t)N * 64 * 4);                 // hpre1 then h2pre
  __hip_bfloat16* ybuf = (__hip_bfloat16*)alloc((size_t)N * 640 * 2); // Y1ext(640) / Y2ext(576)
  if (off > ws_size) return;  // workspace too small: fail gracefully

  hipMemsetAsync(indeg, 0, (size_t)N * 4, stream);
  hipMemsetAsync(sums, 0, 6 * 64 * 8, stream);

  pack_b1t<<<(640 * 32 + 255) / 256, 256, 0, stream>>>(W1, root1, Wskip, B1t);
  pack_b2t<<<(576 * 64 + 255) / 256, 256, 0, stream>>>(W2, root2, B2t);

  const int eblocks = (E + 255) / 256;
  const int nb = (N + 1023) / 1024;
  hist_dst<<<eblocks, 256, 0, stream>>>(ei, E, indeg);
  scan_block<<<nb, 1024, 0, stream>>>(indeg, cursor /*partial*/, bsum, N);
  scan_top<<<1, 1024, 0, stream>>>(bsum, nb);
  scan_add<<<(N + 255) / 256, 256, 0, stream>>>(cursor, bsum, rowptr, indeg /*cursor2*/, N, E);
  edge_scatter<<<eblocks, 256, 0, stream>>>(ei, attr, E, indeg, emeta);

  const int gblocks = (N + 63) / 64;

  // layer 1: Y1ext = x @ [W1(o-major)|root1|Wskip]   (N x 640, bf16)
  gemm_mfma<32, false><<<gblocks, 256, 0, stream>>>(x, B1t, ybuf, N, 640, nullptr, nullptr);

  msg_dst<640, true><<<2048, 256, 0, stream>>>(ybuf, rowptr, emeta, N, agg, out, sums);
  bn_finalize<<<1, 64, 0, stream>>>(sums + 0 * 64, g1, b1, scales + 0 * 64, scales + 1 * 64, N);
  bn_finalize<<<1, 64, 0, stream>>>(sums + 2 * 64, gS, bS, scales + 2 * 64, scales + 3 * 64, N);

  // layer 2: Y2ext = elu(bn1(hpre)) @ [W2(o-major)|root2]   (N x 576, bf16)
  gemm_mfma<64, true><<<gblocks, 256, 0, stream>>>(agg, B2t, ybuf, N, 576, scales + 0 * 64,
                                                   scales + 1 * 64);

  msg_dst<576, false><<<2048, 256, 0, stream>>>(ybuf, rowptr, emeta, N, agg, nullptr,
                                                sums + 4 * 64);
  bn_finalize<<<1, 64, 0, stream>>>(sums + 4 * 64, g2, b2, scales + 4 * 64, scales + 5 * 64, N);

  final_k<<<((N * 64) + 255) / 256, 256, 0, stream>>>(agg, scales + 4 * 64, scales + 5 * 64,
                                                      scales + 2 * 64, scales + 3 * 64, out,
                                                      N * 64);
}

// Round 6
// 921.025 us; speedup vs baseline: 1.5846x; 1.0044x over previous
//
#include <hip/hip_runtime.h>
#include <hip/hip_bf16.h>
#include <cstdint>

#define BN_EPS 1e-5f

typedef __attribute__((ext_vector_type(8))) short bf16x8;
typedef __attribute__((ext_vector_type(4))) float f32x4;

__device__ inline unsigned short f2bf(float f) {
  unsigned int b = __float_as_uint(f);
  b += 0x7FFFu + ((b >> 16) & 1u);  // RNE
  return (unsigned short)(b >> 16);
}
__device__ inline float bf2f(unsigned short u) { return __uint_as_float((unsigned int)u << 16); }

// ---------------- pack weights: bf16, transposed [Ncols][K] ----------------
__global__ void pack_b1t(const float* __restrict__ W1, const float* __restrict__ root1,
                         const float* __restrict__ Wskip, __hip_bfloat16* __restrict__ B1t) {
  int idx = blockIdx.x * blockDim.x + threadIdx.x;
  if (idx >= 640 * 32) return;
  int n = idx >> 5, k = idx & 31;
  float v;
  if (n < 512) v = W1[(n & 7) * (32 * 64) + k * 64 + (n >> 3)];
  else if (n < 576) v = root1[k * 64 + (n - 512)];
  else v = Wskip[k * 64 + (n - 576)];
  ((unsigned short*)B1t)[idx] = f2bf(v);
}

__global__ void pack_b2t(const float* __restrict__ W2, const float* __restrict__ root2,
                         __hip_bfloat16* __restrict__ B2t) {
  int idx = blockIdx.x * blockDim.x + threadIdx.x;
  if (idx >= 576 * 64) return;
  int n = idx >> 6, k = idx & 63;
  float v;
  if (n < 512) v = W2[(n & 7) * (64 * 64) + k * 64 + (n >> 3)];
  else v = root2[k * 64 + (n - 512)];
  ((unsigned short*)B2t)[idx] = f2bf(v);
}

// ---------------- dst-CSR build ----------------
__global__ void hist_dst(const int* __restrict__ ei, int E, int* __restrict__ indeg) {
  int e = blockIdx.x * 256 + threadIdx.x;
  if (e >= E) return;
  atomicAdd(&indeg[ei[E + e]], 1);
}

__global__ __launch_bounds__(1024) void scan_block(const int* __restrict__ in,
                                                   int* __restrict__ part,
                                                   int* __restrict__ bsum, int N) {
  __shared__ int tmp[1024];
  int i = blockIdx.x * 1024 + threadIdx.x;
  int v = (i < N) ? in[i] : 0;
  tmp[threadIdx.x] = v;
  __syncthreads();
  for (int ofs = 1; ofs < 1024; ofs <<= 1) {
    int t = (threadIdx.x >= (unsigned)ofs) ? tmp[threadIdx.x - ofs] : 0;
    __syncthreads();
    tmp[threadIdx.x] += t;
    __syncthreads();
  }
  if (i < N) part[i] = tmp[threadIdx.x] - v;  // exclusive within block
  if (threadIdx.x == 1023) bsum[blockIdx.x] = tmp[1023];
}

__global__ __launch_bounds__(1024) void scan_top(int* __restrict__ bsum, int nb) {
  __shared__ int tmp[1024];
  int v = (threadIdx.x < (unsigned)nb) ? bsum[threadIdx.x] : 0;
  tmp[threadIdx.x] = v;
  __syncthreads();
  for (int ofs = 1; ofs < 1024; ofs <<= 1) {
    int t = (threadIdx.x >= (unsigned)ofs) ? tmp[threadIdx.x - ofs] : 0;
    __syncthreads();
    tmp[threadIdx.x] += t;
    __syncthreads();
  }
  if (threadIdx.x < (unsigned)nb) bsum[threadIdx.x] = tmp[threadIdx.x] - v;  // exclusive
}

__global__ void scan_add(const int* __restrict__ part, const int* __restrict__ bsum,
                         int* __restrict__ rowptr, int* __restrict__ cursor, int N, int E) {
  int i = blockIdx.x * 256 + threadIdx.x;
  if (i < N) {
    int r = part[i] + bsum[i >> 10];
    rowptr[i] = r;
    cursor[i] = r;
  }
  if (i == 0) rowptr[N] = E;
}

// Scatter: per edge (dst-grouped position) store src index + 8 precomputed basis weights (fp32).
__global__ void edge_scatter(const int* __restrict__ ei, const float* __restrict__ attr, int E,
                             int* __restrict__ cursor, int* __restrict__ wsrc,
                             float* __restrict__ wts) {
  int e = blockIdx.x * 256 + threadIdx.x;
  if (e >= E) return;
  int src = ei[e], dst = ei[E + e];
  float u0 = attr[3 * e + 0], u1 = attr[3 * e + 1], u2 = attr[3 * e + 2];
  float p0 = 1.f - u0, p1 = 1.f - u1, p2 = 1.f - u2;
  float w00 = p1 * p2, w10 = u1 * p2, w01 = p1 * u2, w11 = u1 * u2;
  int pos = atomicAdd(&cursor[dst], 1);
  wsrc[pos] = src;
  float4 lo = make_float4(p0 * w00, u0 * w00, p0 * w10, u0 * w10);
  float4 hi = make_float4(p0 * w01, u0 * w01, p0 * w11, u0 * w11);
  *(float4*)&wts[(size_t)pos * 8] = lo;
  *(float4*)&wts[(size_t)pos * 8 + 4] = hi;
}

// ---------------- MFMA GEMM: C(M x Ncols bf16) = A(M x K fp32) @ Bt(Ncols x K bf16)^T ----------
template <int K, bool BN>
__global__ __launch_bounds__(256) void gemm_mfma(const float* __restrict__ A,
                                                 const __hip_bfloat16* __restrict__ Bt,
                                                 __hip_bfloat16* __restrict__ C, int M, int Ncols,
                                                 const float* __restrict__ scale,
                                                 const float* __restrict__ shift) {
  const int tid = threadIdx.x;
  const int lane = tid & 63;
  const int wv = tid >> 6;
  const int rowbase = blockIdx.x * 64 + wv * 16;
  const int m = lane & 15;
  const int quad = lane >> 4;
  const int k0 = quad * 8;

  int ar = rowbase + m;
  if (ar > M - 1) ar = M - 1;
  const float* arow = A + (size_t)ar * K;

  bf16x8 afrag[K / 32];
#pragma unroll
  for (int f = 0; f < K / 32; f++) {
    float v[8];
#pragma unroll
    for (int j = 0; j < 8; j++) v[j] = arow[f * 32 + k0 + j];
    if (BN) {
#pragma unroll
      for (int j = 0; j < 8; j++) {
        float t = v[j] * scale[f * 32 + k0 + j] + shift[f * 32 + k0 + j];
        v[j] = t > 0.f ? t : expm1f(t);
      }
    }
    bf16x8 af;
#pragma unroll
    for (int j = 0; j < 8; j++) af[j] = (short)f2bf(v[j]);
    afrag[f] = af;
  }

  for (int col0 = 0; col0 < Ncols; col0 += 16) {
    f32x4 acc = {0.f, 0.f, 0.f, 0.f};
#pragma unroll
    for (int f = 0; f < K / 32; f++) {
      const __hip_bfloat16* bp = Bt + (size_t)(col0 + m) * K + f * 32 + k0;
      bf16x8 bfrag = *(const bf16x8*)bp;
      acc = __builtin_amdgcn_mfma_f32_16x16x32_bf16(afrag[f], bfrag, acc, 0, 0, 0);
    }
#pragma unroll
    for (int r = 0; r < 4; r++) {
      int gr = rowbase + quad * 4 + r;
      if (gr < M) ((unsigned short*)C)[(size_t)gr * Ncols + col0 + m] = f2bf(acc[r]);
    }
  }
}

// ---------------- dst-grouped message + finish (fused): one wave per dst node ----------------
// Scalarized metadata (readfirstlane bounds -> s_load for wsrc/wts), one vector load per edge,
// unroll-2 with independent accumulators for memory-level parallelism.
template <int YSTRIDE, bool L1>
__global__ __launch_bounds__(256) void msg_dst(const __hip_bfloat16* __restrict__ Y,
                                               const int* __restrict__ rowptr,
                                               const int* __restrict__ wsrc,
                                               const float* __restrict__ wts, int N,
                                               float* __restrict__ hout,
                                               float* __restrict__ sout,
                                               double* __restrict__ sums) {
  const int tid = threadIdx.x;
  const int lane = tid & 63;
  const int wv = tid >> 6;
  const int nwaves = gridDim.x * 4;
  const int lo8 = lane * 8;
  float sh = 0.f, sh2 = 0.f, ss = 0.f, ss2 = 0.f;

  for (int n = blockIdx.x * 4 + wv; n < N; n += nwaves) {
    const int e0 = __builtin_amdgcn_readfirstlane(rowptr[n]);
    const int e1 = __builtin_amdgcn_readfirstlane(rowptr[n + 1]);
    float acc0 = 0.f, acc1 = 0.f;
    int e = e0;
    for (; e + 2 <= e1; e += 2) {
      int s0 = wsrc[e];
      int s1 = wsrc[e + 1];
      union { bf16x8 v8; unsigned short us[8]; } y0, y1;
      y0.v8 = *(const bf16x8*)((const unsigned short*)Y + (size_t)s0 * YSTRIDE + lo8);
      y1.v8 = *(const bf16x8*)((const unsigned short*)Y + (size_t)s1 * YSTRIDE + lo8);
      const float* w0 = wts + (size_t)e * 8;
      float t0 = 0.f, t1 = 0.f;
#pragma unroll
      for (int k = 0; k < 8; k++) t0 += w0[k] * bf2f(y0.us[k]);
#pragma unroll
      for (int k = 0; k < 8; k++) t1 += w0[8 + k] * bf2f(y1.us[k]);
      acc0 += t0;
      acc1 += t1;
    }
    if (e < e1) {
      int s0 = wsrc[e];
      union { bf16x8 v8; unsigned short us[8]; } y0;
      y0.v8 = *(const bf16x8*)((const unsigned short*)Y + (size_t)s0 * YSTRIDE + lo8);
      const float* w0 = wts + (size_t)e * 8;
      float t0 = 0.f;
#pragma unroll
      for (int k = 0; k < 8; k++) t0 += w0[k] * bf2f(y0.us[k]);
      acc0 += t0;
    }
    float deg = (float)(e1 - e0);
    float inv = 1.f / fmaxf(deg, 1.f);
    float h = (acc0 + acc1) * inv +
              bf2f(((const unsigned short*)Y)[(size_t)n * YSTRIDE + 512 + lane]);
    hout[(size_t)n * 64 + lane] = h;
    sh += h; sh2 += h * h;
    if (L1) {
      float s = bf2f(((const unsigned short*)Y)[(size_t)n * YSTRIDE + 576 + lane]);
      sout[(size_t)n * 64 + lane] = s;
      ss += s; ss2 += s * s;
    }
  }

  __shared__ float red[256];
  const int nst = L1 ? 4 : 2;
  float vals[4] = {sh, sh2, ss, ss2};
  for (int v = 0; v < nst; v++) {
    __syncthreads();
    red[tid] = vals[v];
    __syncthreads();
    if (tid < 64) {
      float tot = red[tid] + red[tid + 64] + red[tid + 128] + red[tid + 192];
      atomicAdd(&sums[v * 64 + tid], (double)tot);
    }
  }
}

// ---------------- bn finalize ----------------
__global__ void bn_finalize(const double* __restrict__ sums /*2x64*/, const float* __restrict__ g,
                            const float* __restrict__ b, float* __restrict__ scale,
                            float* __restrict__ shift, int N) {
  int t = threadIdx.x;
  if (t >= 64) return;
  double mean = sums[t] / (double)N;
  double var = sums[64 + t] / (double)N - mean * mean;
  double inv = 1.0 / sqrt(var + (double)BN_EPS);
  float sc = (float)((double)g[t] * inv);
  scale[t] = sc;
  shift[t] = b[t] - (float)mean * sc;
}

// ---------------- epilogue: out = elu(bn2(h2pre) + bnS(spre)); spre lives in d_out ----------------
__global__ __launch_bounds__(256) void final_k(const float* __restrict__ h2pre,
                                               const float* __restrict__ scale2,
                                               const float* __restrict__ shift2,
                                               const float* __restrict__ scaleS,
                                               const float* __restrict__ shiftS,
                                               float* __restrict__ out, int total) {
  int idx = blockIdx.x * 256 + threadIdx.x;
  if (idx >= total) return;
  int ch = idx & 63;
  float h2 = h2pre[idx] * scale2[ch] + shift2[ch];
  float s = out[idx] * scaleS[ch] + shiftS[ch];
  float v = h2 + s;
  out[idx] = v > 0.f ? v : expm1f(v);
}

extern "C" void kernel_launch(void* const* d_in, const int* in_sizes, int n_in,
                              void* d_out, int out_size, void* d_ws, size_t ws_size,
                              hipStream_t stream) {
  const float* x     = (const float*)d_in[0];
  const int*   ei    = (const int*)d_in[1];
  const float* attr  = (const float*)d_in[2];
  const float* W1    = (const float*)d_in[3];
  const float* root1 = (const float*)d_in[4];
  const float* g1    = (const float*)d_in[5];
  const float* b1    = (const float*)d_in[6];
  const float* W2    = (const float*)d_in[7];
  const float* root2 = (const float*)d_in[8];
  const float* g2    = (const float*)d_in[9];
  const float* b2    = (const float*)d_in[10];
  const float* Wskip = (const float*)d_in[11];
  const float* gS    = (const float*)d_in[12];
  const float* bS    = (const float*)d_in[13];
  const int N = in_sizes[0] / 32;
  const int E = in_sizes[1] / 2;
  float* out = (float*)d_out;

  char* ws = (char*)d_ws;
  size_t off = 0;
  auto alloc = [&](size_t bytes) {
    void* p = ws + off;
    off = (off + bytes + 255) & ~(size_t)255;
    return p;
  };
  __hip_bfloat16* B1t = (__hip_bfloat16*)alloc(640 * 32 * 2);
  __hip_bfloat16* B2t = (__hip_bfloat16*)alloc(576 * 64 * 2);
  double* sums   = (double*)alloc(6 * 64 * 8);
  float*  scales = (float*)alloc(6 * 64 * 4);
  int*    indeg  = (int*)alloc((size_t)N * 4);
  int*    rowptr = (int*)alloc(((size_t)N + 1) * 4);
  int*    cursor = (int*)alloc((size_t)N * 4);
  int*    bsum   = (int*)alloc(1024 * 4);
  int*    wsrc   = (int*)alloc((size_t)E * 4);
  float*  wts    = (float*)alloc((size_t)E * 32);
  float*  agg    = (float*)alloc((size_t)N * 64 * 4);                 // hpre1 then h2pre
  __hip_bfloat16* ybuf = (__hip_bfloat16*)alloc((size_t)N * 640 * 2); // Y1ext(640) / Y2ext(576)
  if (off > ws_size) return;  // workspace too small: fail gracefully

  hipMemsetAsync(indeg, 0, (size_t)N * 4, stream);
  hipMemsetAsync(sums, 0, 6 * 64 * 8, stream);

  pack_b1t<<<(640 * 32 + 255) / 256, 256, 0, stream>>>(W1, root1, Wskip, B1t);
  pack_b2t<<<(576 * 64 + 255) / 256, 256, 0, stream>>>(W2, root2, B2t);

  const int eblocks = (E + 255) / 256;
  const int nb = (N + 1023) / 1024;
  hist_dst<<<eblocks, 256, 0, stream>>>(ei, E, indeg);
  scan_block<<<nb, 1024, 0, stream>>>(indeg, cursor /*partial*/, bsum, N);
  scan_top<<<1, 1024, 0, stream>>>(bsum, nb);
  scan_add<<<(N + 255) / 256, 256, 0, stream>>>(cursor, bsum, rowptr, indeg /*cursor2*/, N, E);
  edge_scatter<<<eblocks, 256, 0, stream>>>(ei, attr, E, indeg, wsrc, wts);

  const int gblocks = (N + 63) / 64;

  // layer 1: Y1ext = x @ [W1(o-major)|root1|Wskip]   (N x 640, bf16)
  gemm_mfma<32, false><<<gblocks, 256, 0, stream>>>(x, B1t, ybuf, N, 640, nullptr, nullptr);

  msg_dst<640, true><<<2048, 256, 0, stream>>>(ybuf, rowptr, wsrc, wts, N, agg, out, sums);
  bn_finalize<<<1, 64, 0, stream>>>(sums + 0 * 64, g1, b1, scales + 0 * 64, scales + 1 * 64, N);
  bn_finalize<<<1, 64, 0, stream>>>(sums + 2 * 64, gS, bS, scales + 2 * 64, scales + 3 * 64, N);

  // layer 2: Y2ext = elu(bn1(hpre)) @ [W2(o-major)|root2]   (N x 576, bf16)
  gemm_mfma<64, true><<<gblocks, 256, 0, stream>>>(agg, B2t, ybuf, N, 576, scales + 0 * 64,
                                                   scales + 1 * 64);

  msg_dst<576, false><<<2048, 256, 0, stream>>>(ybuf, rowptr, wsrc, wts, N, agg, nullptr,
                                                sums + 4 * 64);
  bn_finalize<<<1, 64, 0, stream>>>(sums + 4 * 64, g2, b2, scales + 4 * 64, scales + 5 * 64, N);

  final_k<<<((N * 64) + 255) / 256, 256, 0, stream>>>(agg, scales + 4 * 64, scales + 5 * 64,
                                                      scales + 2 * 64, scales + 3 * 64, out,
                                                      N * 64);
}

// Round 7
// 711.010 us; speedup vs baseline: 2.0527x; 1.2954x over previous
//
#include <hip/hip_runtime.h>
#include <hip/hip_bf16.h>
#include <cstdint>

#define BN_EPS 1e-5f

typedef __attribute__((ext_vector_type(8))) short bf16x8;
typedef __attribute__((ext_vector_type(4))) float f32x4;
typedef __attribute__((ext_vector_type(2))) float f32x2;

__device__ inline unsigned short f2bf(float f) {
  unsigned int b = __float_as_uint(f);
  b += 0x7FFFu + ((b >> 16) & 1u);  // RNE
  return (unsigned short)(b >> 16);
}
__device__ inline float bf2f(unsigned short u) { return __uint_as_float((unsigned int)u << 16); }
__device__ inline unsigned char f2fp8(float f) {
  int p = __builtin_amdgcn_cvt_pk_fp8_f32(f, f, 0, false);  // OCP e4m3 on gfx950
  return (unsigned char)(p & 0xFF);
}

// ---------------- pack weights: bf16, transposed [Ncols][K] ----------------
__global__ void pack_b1t(const float* __restrict__ W1, const float* __restrict__ root1,
                         const float* __restrict__ Wskip, __hip_bfloat16* __restrict__ B1t) {
  int idx = blockIdx.x * blockDim.x + threadIdx.x;
  if (idx >= 640 * 32) return;
  int n = idx >> 5, k = idx & 31;
  float v;
  if (n < 512) v = W1[(n & 7) * (32 * 64) + k * 64 + (n >> 3)];
  else if (n < 576) v = root1[k * 64 + (n - 512)];
  else v = Wskip[k * 64 + (n - 576)];
  ((unsigned short*)B1t)[idx] = f2bf(v);
}

__global__ void pack_b2t(const float* __restrict__ W2, const float* __restrict__ root2,
                         __hip_bfloat16* __restrict__ B2t) {
  int idx = blockIdx.x * blockDim.x + threadIdx.x;
  if (idx >= 576 * 64) return;
  int n = idx >> 6, k = idx & 63;
  float v;
  if (n < 512) v = W2[(n & 7) * (64 * 64) + k * 64 + (n >> 3)];
  else v = root2[k * 64 + (n - 512)];
  ((unsigned short*)B2t)[idx] = f2bf(v);
}

// ---------------- dst-CSR build ----------------
__global__ void hist_dst(const int* __restrict__ ei, int E, int* __restrict__ indeg) {
  int e = blockIdx.x * 256 + threadIdx.x;
  if (e >= E) return;
  atomicAdd(&indeg[ei[E + e]], 1);
}

__global__ __launch_bounds__(1024) void scan_block(const int* __restrict__ in,
                                                   int* __restrict__ part,
                                                   int* __restrict__ bsum, int N) {
  __shared__ int tmp[1024];
  int i = blockIdx.x * 1024 + threadIdx.x;
  int v = (i < N) ? in[i] : 0;
  tmp[threadIdx.x] = v;
  __syncthreads();
  for (int ofs = 1; ofs < 1024; ofs <<= 1) {
    int t = (threadIdx.x >= (unsigned)ofs) ? tmp[threadIdx.x - ofs] : 0;
    __syncthreads();
    tmp[threadIdx.x] += t;
    __syncthreads();
  }
  if (i < N) part[i] = tmp[threadIdx.x] - v;  // exclusive within block
  if (threadIdx.x == 1023) bsum[blockIdx.x] = tmp[1023];
}

__global__ __launch_bounds__(1024) void scan_top(int* __restrict__ bsum, int nb) {
  __shared__ int tmp[1024];
  int v = (threadIdx.x < (unsigned)nb) ? bsum[threadIdx.x] : 0;
  tmp[threadIdx.x] = v;
  __syncthreads();
  for (int ofs = 1; ofs < 1024; ofs <<= 1) {
    int t = (threadIdx.x >= (unsigned)ofs) ? tmp[threadIdx.x - ofs] : 0;
    __syncthreads();
    tmp[threadIdx.x] += t;
    __syncthreads();
  }
  if (threadIdx.x < (unsigned)nb) bsum[threadIdx.x] = tmp[threadIdx.x] - v;  // exclusive
}

__global__ void scan_add(const int* __restrict__ part, const int* __restrict__ bsum,
                         int* __restrict__ rowptr, int* __restrict__ cursor, int N, int E) {
  int i = blockIdx.x * 256 + threadIdx.x;
  if (i < N) {
    int r = part[i] + bsum[i >> 10];
    rowptr[i] = r;
    cursor[i] = r;
  }
  if (i == 0) rowptr[N] = E;
}

// Scatter: per edge (dst-grouped position) store src index + 8 precomputed basis weights (fp32).
__global__ void edge_scatter(const int* __restrict__ ei, const float* __restrict__ attr, int E,
                             int* __restrict__ cursor, int* __restrict__ wsrc,
                             float* __restrict__ wts) {
  int e = blockIdx.x * 256 + threadIdx.x;
  if (e >= E) return;
  int src = ei[e], dst = ei[E + e];
  float u0 = attr[3 * e + 0], u1 = attr[3 * e + 1], u2 = attr[3 * e + 2];
  float p0 = 1.f - u0, p1 = 1.f - u1, p2 = 1.f - u2;
  float w00 = p1 * p2, w10 = u1 * p2, w01 = p1 * u2, w11 = u1 * u2;
  int pos = atomicAdd(&cursor[dst], 1);
  wsrc[pos] = src;
  float4 lo = make_float4(p0 * w00, u0 * w00, p0 * w10, u0 * w10);
  float4 hi = make_float4(p0 * w01, u0 * w01, p0 * w11, u0 * w11);
  *(float4*)&wts[(size_t)pos * 8] = lo;
  *(float4*)&wts[(size_t)pos * 8 + 4] = hi;
}

// ---------------- MFMA GEMM: [Yq fp8 (cols 0..511) | RS bf16 (cols 512+)] = A @ Bt^T ----------
// A: M x K fp32. Bt: Ncols x K bf16. Yq stride 512 (fp8); RS stride rss (bf16).
template <int K, bool BN>
__global__ __launch_bounds__(256) void gemm_mfma(const float* __restrict__ A,
                                                 const __hip_bfloat16* __restrict__ Bt,
                                                 unsigned char* __restrict__ Yq,
                                                 __hip_bfloat16* __restrict__ RS, int M,
                                                 int Ncols, int rss,
                                                 const float* __restrict__ scale,
                                                 const float* __restrict__ shift) {
  const int tid = threadIdx.x;
  const int lane = tid & 63;
  const int wv = tid >> 6;
  const int rowbase = blockIdx.x * 64 + wv * 16;
  const int m = lane & 15;
  const int quad = lane >> 4;
  const int k0 = quad * 8;

  int ar = rowbase + m;
  if (ar > M - 1) ar = M - 1;
  const float* arow = A + (size_t)ar * K;

  bf16x8 afrag[K / 32];
#pragma unroll
  for (int f = 0; f < K / 32; f++) {
    float v[8];
#pragma unroll
    for (int j = 0; j < 8; j++) v[j] = arow[f * 32 + k0 + j];
    if (BN) {
#pragma unroll
      for (int j = 0; j < 8; j++) {
        float t = v[j] * scale[f * 32 + k0 + j] + shift[f * 32 + k0 + j];
        v[j] = t > 0.f ? t : expm1f(t);
      }
    }
    bf16x8 af;
#pragma unroll
    for (int j = 0; j < 8; j++) af[j] = (short)f2bf(v[j]);
    afrag[f] = af;
  }

  for (int col0 = 0; col0 < Ncols; col0 += 16) {
    f32x4 acc = {0.f, 0.f, 0.f, 0.f};
#pragma unroll
    for (int f = 0; f < K / 32; f++) {
      const __hip_bfloat16* bp = Bt + (size_t)(col0 + m) * K + f * 32 + k0;
      bf16x8 bfrag = *(const bf16x8*)bp;
      acc = __builtin_amdgcn_mfma_f32_16x16x32_bf16(afrag[f], bfrag, acc, 0, 0, 0);
    }
    const int col = col0 + m;
#pragma unroll
    for (int r = 0; r < 4; r++) {
      int gr = rowbase + quad * 4 + r;
      if (gr < M) {
        if (col < 512) Yq[(size_t)gr * 512 + col] = f2fp8(acc[r]);
        else ((unsigned short*)RS)[(size_t)gr * rss + (col - 512)] = f2bf(acc[r]);
      }
    }
  }
}

// ---------------- dst-grouped message + finish (fused): one wave per dst node ----------------
// Yq: fp8 table N x 512 (row = 512 B, lane reads 8 B); RS: bf16 root(+skip) table.
template <bool L1>
__global__ __launch_bounds__(256) void msg_dst(const unsigned char* __restrict__ Yq,
                                               const __hip_bfloat16* __restrict__ RS,
                                               const int* __restrict__ rowptr,
                                               const int* __restrict__ wsrc,
                                               const float* __restrict__ wts, int N,
                                               float* __restrict__ hout,
                                               float* __restrict__ sout,
                                               double* __restrict__ sums) {
  const int tid = threadIdx.x;
  const int lane = tid & 63;
  const int wv = tid >> 6;
  const int nwaves = gridDim.x * 4;
  const int lo8 = lane * 8;
  const int RSS = L1 ? 128 : 64;
  float sh = 0.f, sh2 = 0.f, ss = 0.f, ss2 = 0.f;

  for (int n = blockIdx.x * 4 + wv; n < N; n += nwaves) {
    const int e0 = __builtin_amdgcn_readfirstlane(rowptr[n]);
    const int e1 = __builtin_amdgcn_readfirstlane(rowptr[n + 1]);
    float acc0 = 0.f, acc1 = 0.f;
    int e = e0;
    for (; e + 2 <= e1; e += 2) {
      int s0 = wsrc[e];
      int s1 = wsrc[e + 1];
      uint2 q0 = *(const uint2*)(Yq + (size_t)s0 * 512 + lo8);
      uint2 q1 = *(const uint2*)(Yq + (size_t)s1 * 512 + lo8);
      const float* w0 = wts + (size_t)e * 8;
      f32x2 a, b;
      a = __builtin_amdgcn_cvt_pk_f32_fp8((int)q0.x, false);
      b = __builtin_amdgcn_cvt_pk_f32_fp8((int)q0.x, true);
      float t0 = w0[0] * a.x + w0[1] * a.y + w0[2] * b.x + w0[3] * b.y;
      a = __builtin_amdgcn_cvt_pk_f32_fp8((int)q0.y, false);
      b = __builtin_amdgcn_cvt_pk_f32_fp8((int)q0.y, true);
      t0 += w0[4] * a.x + w0[5] * a.y + w0[6] * b.x + w0[7] * b.y;
      a = __builtin_amdgcn_cvt_pk_f32_fp8((int)q1.x, false);
      b = __builtin_amdgcn_cvt_pk_f32_fp8((int)q1.x, true);
      float t1 = w0[8] * a.x + w0[9] * a.y + w0[10] * b.x + w0[11] * b.y;
      a = __builtin_amdgcn_cvt_pk_f32_fp8((int)q1.y, false);
      b = __builtin_amdgcn_cvt_pk_f32_fp8((int)q1.y, true);
      t1 += w0[12] * a.x + w0[13] * a.y + w0[14] * b.x + w0[15] * b.y;
      acc0 += t0;
      acc1 += t1;
    }
    if (e < e1) {
      int s0 = wsrc[e];
      uint2 q0 = *(const uint2*)(Yq + (size_t)s0 * 512 + lo8);
      const float* w0 = wts + (size_t)e * 8;
      f32x2 a, b;
      a = __builtin_amdgcn_cvt_pk_f32_fp8((int)q0.x, false);
      b = __builtin_amdgcn_cvt_pk_f32_fp8((int)q0.x, true);
      float t0 = w0[0] * a.x + w0[1] * a.y + w0[2] * b.x + w0[3] * b.y;
      a = __builtin_amdgcn_cvt_pk_f32_fp8((int)q0.y, false);
      b = __builtin_amdgcn_cvt_pk_f32_fp8((int)q0.y, true);
      t0 += w0[4] * a.x + w0[5] * a.y + w0[6] * b.x + w0[7] * b.y;
      acc0 += t0;
    }
    float deg = (float)(e1 - e0);
    float inv = 1.f / fmaxf(deg, 1.f);
    float h = (acc0 + acc1) * inv +
              bf2f(((const unsigned short*)RS)[(size_t)n * RSS + lane]);
    hout[(size_t)n * 64 + lane] = h;
    sh += h; sh2 += h * h;
    if (L1) {
      float s = bf2f(((const unsigned short*)RS)[(size_t)n * RSS + 64 + lane]);
      sout[(size_t)n * 64 + lane] = s;
      ss += s; ss2 += s * s;
    }
  }

  __shared__ float red[256];
  const int nst = L1 ? 4 : 2;
  float vals[4] = {sh, sh2, ss, ss2};
  for (int v = 0; v < nst; v++) {
    __syncthreads();
    red[tid] = vals[v];
    __syncthreads();
    if (tid < 64) {
      float tot = red[tid] + red[tid + 64] + red[tid + 128] + red[tid + 192];
      atomicAdd(&sums[v * 64 + tid], (double)tot);
    }
  }
}

// ---------------- bn finalize ----------------
__global__ void bn_finalize(const double* __restrict__ sums /*2x64*/, const float* __restrict__ g,
                            const float* __restrict__ b, float* __restrict__ scale,
                            float* __restrict__ shift, int N) {
  int t = threadIdx.x;
  if (t >= 64) return;
  double mean = sums[t] / (double)N;
  double var = sums[64 + t] / (double)N - mean * mean;
  double inv = 1.0 / sqrt(var + (double)BN_EPS);
  float sc = (float)((double)g[t] * inv);
  scale[t] = sc;
  shift[t] = b[t] - (float)mean * sc;
}

// ---------------- epilogue: out = elu(bn2(h2pre) + bnS(spre)); spre lives in d_out ----------------
__global__ __launch_bounds__(256) void final_k(const float* __restrict__ h2pre,
                                               const float* __restrict__ scale2,
                                               const float* __restrict__ shift2,
                                               const float* __restrict__ scaleS,
                                               const float* __restrict__ shiftS,
                                               float* __restrict__ out, int total) {
  int idx = blockIdx.x * 256 + threadIdx.x;
  if (idx >= total) return;
  int ch = idx & 63;
  float h2 = h2pre[idx] * scale2[ch] + shift2[ch];
  float s = out[idx] * scaleS[ch] + shiftS[ch];
  float v = h2 + s;
  out[idx] = v > 0.f ? v : expm1f(v);
}

extern "C" void kernel_launch(void* const* d_in, const int* in_sizes, int n_in,
                              void* d_out, int out_size, void* d_ws, size_t ws_size,
                              hipStream_t stream) {
  const float* x     = (const float*)d_in[0];
  const int*   ei    = (const int*)d_in[1];
  const float* attr  = (const float*)d_in[2];
  const float* W1    = (const float*)d_in[3];
  const float* root1 = (const float*)d_in[4];
  const float* g1    = (const float*)d_in[5];
  const float* b1    = (const float*)d_in[6];
  const float* W2    = (const float*)d_in[7];
  const float* root2 = (const float*)d_in[8];
  const float* g2    = (const float*)d_in[9];
  const float* b2    = (const float*)d_in[10];
  const float* Wskip = (const float*)d_in[11];
  const float* gS    = (const float*)d_in[12];
  const float* bS    = (const float*)d_in[13];
  const int N = in_sizes[0] / 32;
  const int E = in_sizes[1] / 2;
  float* out = (float*)d_out;

  char* ws = (char*)d_ws;
  size_t off = 0;
  auto alloc = [&](size_t bytes) {
    void* p = ws + off;
    off = (off + bytes + 255) & ~(size_t)255;
    return p;
  };
  __hip_bfloat16* B1t = (__hip_bfloat16*)alloc(640 * 32 * 2);
  __hip_bfloat16* B2t = (__hip_bfloat16*)alloc(576 * 64 * 2);
  double* sums   = (double*)alloc(6 * 64 * 8);
  float*  scales = (float*)alloc(6 * 64 * 4);
  int*    indeg  = (int*)alloc((size_t)N * 4);
  int*    rowptr = (int*)alloc(((size_t)N + 1) * 4);
  int*    cursor = (int*)alloc((size_t)N * 4);
  int*    bsum   = (int*)alloc(1024 * 4);
  int*    wsrc   = (int*)alloc((size_t)E * 4);
  float*  wts    = (float*)alloc((size_t)E * 32);
  float*  agg    = (float*)alloc((size_t)N * 64 * 4);        // hpre1 then h2pre
  unsigned char*  Yq = (unsigned char*)alloc((size_t)N * 512);      // fp8 gather table
  __hip_bfloat16* RS = (__hip_bfloat16*)alloc((size_t)N * 128 * 2); // root(+skip) bf16
  if (off > ws_size) return;  // workspace too small: fail gracefully

  hipMemsetAsync(indeg, 0, (size_t)N * 4, stream);
  hipMemsetAsync(sums, 0, 6 * 64 * 8, stream);

  pack_b1t<<<(640 * 32 + 255) / 256, 256, 0, stream>>>(W1, root1, Wskip, B1t);
  pack_b2t<<<(576 * 64 + 255) / 256, 256, 0, stream>>>(W2, root2, B2t);

  const int eblocks = (E + 255) / 256;
  const int nb = (N + 1023) / 1024;
  hist_dst<<<eblocks, 256, 0, stream>>>(ei, E, indeg);
  scan_block<<<nb, 1024, 0, stream>>>(indeg, cursor /*partial*/, bsum, N);
  scan_top<<<1, 1024, 0, stream>>>(bsum, nb);
  scan_add<<<(N + 255) / 256, 256, 0, stream>>>(cursor, bsum, rowptr, indeg /*cursor2*/, N, E);
  edge_scatter<<<eblocks, 256, 0, stream>>>(ei, attr, E, indeg, wsrc, wts);

  const int gblocks = (N + 63) / 64;

  // layer 1: [Yq|RS] = x @ [W1(o-major)|root1|Wskip]
  gemm_mfma<32, false><<<gblocks, 256, 0, stream>>>(x, B1t, Yq, RS, N, 640, 128, nullptr,
                                                    nullptr);

  msg_dst<true><<<2048, 256, 0, stream>>>(Yq, RS, rowptr, wsrc, wts, N, agg, out, sums);
  bn_finalize<<<1, 64, 0, stream>>>(sums + 0 * 64, g1, b1, scales + 0 * 64, scales + 1 * 64, N);
  bn_finalize<<<1, 64, 0, stream>>>(sums + 2 * 64, gS, bS, scales + 2 * 64, scales + 3 * 64, N);

  // layer 2: [Yq|RS] = elu(bn1(hpre)) @ [W2(o-major)|root2]
  gemm_mfma<64, true><<<gblocks, 256, 0, stream>>>(agg, B2t, Yq, RS, N, 576, 64,
                                                   scales + 0 * 64, scales + 1 * 64);

  msg_dst<false><<<2048, 256, 0, stream>>>(Yq, RS, rowptr, wsrc, wts, N, agg, nullptr,
                                           sums + 4 * 64);
  bn_finalize<<<1, 64, 0, stream>>>(sums + 4 * 64, g2, b2, scales + 4 * 64, scales + 5 * 64, N);

  final_k<<<((N * 64) + 255) / 256, 256, 0, stream>>>(agg, scales + 4 * 64, scales + 5 * 64,
                                                      scales + 2 * 64, scales + 3 * 64, out,
                                                      N * 64);
}